// Round 20
// baseline (251.447 us; speedup 1.0000x reference)
//
#include <hip/hip_runtime.h>

typedef unsigned short u16;
typedef unsigned char u8;
typedef __attribute__((ext_vector_type(4))) float f32x4;

#define B_ROWS 1024
#define DIM 512
#define QN 131072
#define TOPK 32
#define NCLS 10
#define TAUS 35.84f   /* 0.14 * 256 (both operands scaled x16) */
#define CAP 1024
#define FP8SCALE 16.0f

#define S_VMCNT(N) asm volatile("s_waitcnt vmcnt(" #N ")" ::: "memory")
#define S_BAR() asm volatile("s_barrier" ::: "memory")
#define S_LGKM0() asm volatile("s_waitcnt lgkmcnt(0)" ::: "memory")

__device__ __forceinline__ void gload_lds16(const void* gsrc, void* ldst) {
  __builtin_amdgcn_global_load_lds(
      (const __attribute__((address_space(1))) void*)gsrc,
      (__attribute__((address_space(3))) void*)ldst, 16, 0, 0);
}

// pack 4 floats -> 4 fp8 e4m3 bytes (HW cvt). Same packer for A and B, so
// any byte-order convention cancels in the dot product.
__device__ __forceinline__ int pk4(float a, float b, float c, float d) {
  int w = __builtin_amdgcn_cvt_pk_fp8_f32(a, b, 0, false);
  w = __builtin_amdgcn_cvt_pk_fp8_f32(c, d, w, true);
  return w;
}

// ---------------------------------------------------------------- normalize x
// fp32 normalized row -> xn; fp8(x16) k-permuted row -> xnb8; zeroes cnt.
// Permuted layout per 64-k chunk c: 16B slot t = {k c*64+t*8..+8} ++
// {k c*64+32+t*8..+8}.
__global__ __launch_bounds__(256) void normalize_x(const float* __restrict__ x,
                                                   float* __restrict__ xn,
                                                   u8* __restrict__ xnb8,
                                                   int* __restrict__ cnt) {
  int row = blockIdx.x;
  int tid = threadIdx.x;
  __shared__ float xs[DIM];
  __shared__ float wsum[4];
  if (tid == 0) cnt[row] = 0;
  float2 v = ((const float2*)(x + (size_t)row * DIM))[tid];
  float ss = v.x * v.x + v.y * v.y;
  #pragma unroll
  for (int o = 32; o; o >>= 1) ss += __shfl_xor(ss, o);
  if ((tid & 63) == 0) wsum[tid >> 6] = ss;
  __syncthreads();
  float tot = wsum[0] + wsum[1] + wsum[2] + wsum[3];
  float scale = 1.0f / fmaxf(sqrtf(tot), 1e-12f);
  float2 o2; o2.x = v.x * scale; o2.y = v.y * scale;
  ((float2*)(xn + (size_t)row * DIM))[tid] = o2;
  xs[2 * tid] = o2.x; xs[2 * tid + 1] = o2.y;
  __syncthreads();
  if (tid < 32) {  // 32 slots of 16B per row (k-permuted fp8)
    int c = tid >> 2, t4 = tid & 3;
    int k0 = c * 64 + t4 * 8;
    int4 w;
    w.x = pk4(xs[k0+0]*FP8SCALE, xs[k0+1]*FP8SCALE, xs[k0+2]*FP8SCALE, xs[k0+3]*FP8SCALE);
    w.y = pk4(xs[k0+4]*FP8SCALE, xs[k0+5]*FP8SCALE, xs[k0+6]*FP8SCALE, xs[k0+7]*FP8SCALE);
    w.z = pk4(xs[k0+32]*FP8SCALE, xs[k0+33]*FP8SCALE, xs[k0+34]*FP8SCALE, xs[k0+35]*FP8SCALE);
    w.w = pk4(xs[k0+36]*FP8SCALE, xs[k0+37]*FP8SCALE, xs[k0+38]*FP8SCALE, xs[k0+39]*FP8SCALE);
    ((int4*)(xnb8 + (size_t)row * DIM))[tid] = w;
  }
}

// ---------------------- fp8 MFMA GEMM + in-kernel B conversion + filter
// R19 per-tile pipeline VERBATIM (proven 177.4us, absmax 0), now PERSISTENT:
// 512 blocks (2/CU), each walks 8 column-panel tiles with a FIXED row-tile
// (panels cset, cset+16, ..., cset+112 within its XCD -> XCD locality kept,
// A-tile L2-hot across tiles). Cross-tile race audit (no extra fences):
//  - LDS WAR at tile boundary: last slot-0 reads retire before h=6's lgkm0,
//    slot-1 reads before h=7's MFMA-use waits; both precede h=7's BARRIER,
//    which all waves pass before any wave runs the next prologue.
//  - next prologue's vmcnt(2) is count-correct regardless of the variable
//    epilogue atomic count: queue=[epilogue VMEM..., PB(0)x4, A(0)x2];
//    vmcnt(2) retires everything older than the newest 2 (=A(0)) -- i.e.
//    PB(0) AND all epilogue ops (oldest-first retirement).
//  - loop-h0's vmcnt(4) then sees [A(0)x2, PB(1)x4]: the R19 steady state.
// NOTE (R13/R16): 32x32 fp8 shapes incompatible with this layout. NOTE
// (R17): mid-step writeB / no-setprio / 8-lane rescore all regress.
__global__ __launch_bounds__(512, 4) void gemm_filter(const u8* __restrict__ xnb8,
                                                      const float* __restrict__ mem,
                                                      int* __restrict__ cnt,
                                                      int* __restrict__ ccol) {
  __shared__ __attribute__((aligned(16))) u8 As[2][16384];
  __shared__ __attribute__((aligned(16))) u8 Bs[2][8192];
  int bid = blockIdx.x;          // 512 blocks
  int xcd = bid & 7;
  int j = bid >> 3;              // 0..63 within XCD
  int rowt = j & 3;
  int cset = j >> 2;             // 0..15
  int row0 = rowt * 256;
  int tid = threadIdx.x;
  int lane = tid & 63;
  int wv = tid >> 6;             // 0..7
  int wr = wv >> 1, wc = wv & 1;

  // staging geometry: logical k-slot sg = (tid&3) ^ ((r>>1)&3); A chunk jj
  // covers row r = jj*128 + (tid>>2); B covers row r = tid>>2.
  int sg = (tid & 3) ^ ((tid >> 3) & 3);
  const u8* gAb = xnb8 + (size_t)(row0 + (tid >> 2)) * DIM + sg * 16;
  // B base for tile t: colt = xcd*128 + cset + 16*t -> col0 = colt*128
  const float* gB0 = mem + (size_t)((xcd * 128 + cset) * 128 + (tid >> 2)) * DIM + sg * 8;
  const size_t gBstride = (size_t)16 * 128 * DIM;   // +16 panels per tile

  // read side: lane L = row-within-16; phys slot = g ^ ((L>>1)&3)
  int L = lane & 15;
  int g = lane >> 4;
  int phys = g ^ ((L >> 1) & 3);
  int offA = (wr * 64 + L) * 64 + phys * 16;   // bytes, + m*1024
  int offB = (wc * 64 + L) * 64 + phys * 16;   // bytes, + n*1024

  union I4L { int4 v; long l[2]; };
  float4 pb[4];  // B prefetch regs: 16 floats (16 VGPR)

  auto stageA = [&](int h) {
    int slot = h & 1;
    #pragma unroll
    for (int jj = 0; jj < 2; ++jj)
      gload_lds16(gAb + (size_t)jj * 65536 + h * 64,
                  &As[slot][jj * 8192 + tid * 16]);
  };
  auto writeB = [&](int h) {
    int slot = h & 1;
    int4 w;
    w.x = pk4(pb[0].x*FP8SCALE, pb[0].y*FP8SCALE, pb[0].z*FP8SCALE, pb[0].w*FP8SCALE);
    w.y = pk4(pb[1].x*FP8SCALE, pb[1].y*FP8SCALE, pb[1].z*FP8SCALE, pb[1].w*FP8SCALE);
    w.z = pk4(pb[2].x*FP8SCALE, pb[2].y*FP8SCALE, pb[2].z*FP8SCALE, pb[2].w*FP8SCALE);
    w.w = pk4(pb[3].x*FP8SCALE, pb[3].y*FP8SCALE, pb[3].z*FP8SCALE, pb[3].w*FP8SCALE);
    *(int4*)&Bs[slot][tid * 16] = w;
  };

  for (int t = 0; t < 8; ++t) {
    const float* gB = gB0 + (size_t)t * gBstride;
    int col0 = (xcd * 128 + cset + 16 * t) * 128;

    auto issuePB = [&](int h) {
      const float4* s = (const float4*)(gB + h * 64);
      pb[0] = s[0]; pb[1] = s[1];   // k sg*8..+8
      pb[2] = s[8]; pb[3] = s[9];   // k 32+sg*8..+8
    };

    f32x4 acc[4][4];
    #pragma unroll
    for (int m = 0; m < 4; ++m)
      #pragma unroll
      for (int n = 0; n < 4; ++n) acc[m][n] = (f32x4){0.f, 0.f, 0.f, 0.f};

    // prologue: PB(0) first, then A(0); vmcnt(2) retires PB(0) (and any
    // older epilogue VMEM from tile t-1); A(0) keeps flying.
    issuePB(0); stageA(0);
    S_VMCNT(2);
    writeB(0);
    issuePB(1);
    S_LGKM0();

    #pragma unroll
    for (int h = 0; h < 8; ++h) {
      if (h < 7) { S_VMCNT(4); }   // retires A(h)x2; keeps PB(h+1)x4 flying
      else { S_VMCNT(0); }         // h=7: drains A(7)
      S_BAR();
      if (h < 7) stageA(h + 1);
      const u8* Ab = &As[h & 1][0];
      const u8* Bb = &Bs[h & 1][0];
      I4L av[4], bv[4];
      #pragma unroll
      for (int m = 0; m < 4; ++m) av[m].v = *(const int4*)(Ab + offA + m * 1024);
      #pragma unroll
      for (int n = 0; n < 4; ++n) bv[n].v = *(const int4*)(Bb + offB + n * 1024);
      __builtin_amdgcn_s_setprio(1);
      #pragma unroll
      for (int m = 0; m < 4; ++m)
        #pragma unroll
        for (int n = 0; n < 4; ++n)
          acc[m][n] = __builtin_amdgcn_mfma_f32_16x16x32_fp8_fp8(
              av[m].l[0], bv[n].l[0], acc[m][n], 0, 0, 0);
      #pragma unroll
      for (int m = 0; m < 4; ++m)
        #pragma unroll
        for (int n = 0; n < 4; ++n)
          acc[m][n] = __builtin_amdgcn_mfma_f32_16x16x32_fp8_fp8(
              av[m].l[1], bv[n].l[1], acc[m][n], 0, 0, 0);
      __builtin_amdgcn_s_setprio(0);
      if (h < 7) {
        S_VMCNT(2);                // retires PB(h+1)x4; keeps A(h+1)x2 flying
        writeB(h + 1);
        if (h < 6) issuePB(h + 2);
        S_LGKM0();                 // ds ops retired before next barrier
      }
    }

    // epilogue: D row=(lane>>4)*4+q, col=lane&15 (dtype-independent layout)
    int rbase = row0 + wr * 64 + (lane >> 4) * 4;
    int cbase = col0 + wc * 64 + (lane & 15);
    #pragma unroll
    for (int m = 0; m < 4; ++m)
      #pragma unroll
      for (int n = 0; n < 4; ++n)
        #pragma unroll
        for (int q = 0; q < 4; ++q) {
          float v = acc[m][n][q];
          if (v > TAUS) {
            int grow = rbase + m * 16 + q;
            int gcol = cbase + n * 16;
            int idx = atomicAdd(&cnt[grow], 1);
            if (idx < CAP) ccol[(size_t)grow * CAP + idx] = gcol;
          }
        }
  }
}

// ------------------------------- exact rescore + top-32 + softmax vote
// (R15 VERBATIM -- validated absmax 0.0; 16-lane groups: R17 showed 8-lane
// regresses ~+19us)
__global__ __launch_bounds__(256) void rescore_vote(const float* __restrict__ xn,
                                                    const float* __restrict__ mem,
                                                    const int* __restrict__ labels,
                                                    const int* __restrict__ cnt,
                                                    const int* __restrict__ ccol,
                                                    float* __restrict__ out) {
  int row = blockIdx.x;
  int tid = threadIdx.x;
  int gid = tid >> 4;          // 16 groups
  int gl = tid & 15;           // lane within group
  __shared__ __attribute__((aligned(16))) float xs[DIM];
  __shared__ double sv[CAP];
  __shared__ int sc[CAP];
  __shared__ double selv[TOPK];
  __shared__ int selc[TOPK];
  __shared__ double wv32[TOPK];
  __shared__ int slab[TOPK];

  ((float2*)xs)[tid] = ((const float2*)(xn + (size_t)row * DIM))[tid];
  if (tid < TOPK) { selv[tid] = -1e300; selc[tid] = 0; }
  int count = cnt[row];
  if (count > CAP) count = CAP;
  __syncthreads();

  // dot phase: one 16-lane group per candidate, fp64 accumulate
  for (int c = gid; c < count; c += 16) {
    int col = ccol[(size_t)row * CAP + c];
    const float4* mp = (const float4*)(mem + (size_t)col * DIM);
    const float4* xp = (const float4*)xs;
    double p = 0.0;
    #pragma unroll
    for (int u = 0; u < 8; ++u) {
      float4 mv = mp[u * 16 + gl];
      float4 xv = xp[u * 16 + gl];
      p += (double)mv.x * xv.x + (double)mv.y * xv.y +
           (double)mv.z * xv.z + (double)mv.w * xv.w;
    }
    #pragma unroll
    for (int o = 8; o; o >>= 1) p += __shfl_xor(p, o);
    if (gl == 0) { sv[c] = p; sc[c] = col; }
  }
  __syncthreads();

  // rank-based top-32: rank = #{j: v_j > v or (v_j==v && col_j < col)}
  for (int c = tid; c < count; c += 256) {
    double v = sv[c]; int cc = sc[c];
    int r = 0;
    for (int j = 0; j < count; ++j) {
      double vj = sv[j]; int cj = sc[j];
      r += (vj > v) || (vj == v && cj < cc);
    }
    if (r < TOPK) { selv[r] = v; selc[r] = cc; }
  }
  __syncthreads();

  // softmax(sim/0.1) + one-hot vote
  if (tid < TOPK) {
    slab[tid] = labels[selc[tid]];
    double e = exp((selv[tid] - selv[0]) * 10.0);
    double s = e;
    #pragma unroll
    for (int o = 16; o; o >>= 1) s += __shfl_xor(s, o, 32);
    wv32[tid] = e / s;
  }
  __syncthreads();
  if (tid < NCLS) {
    double a = 0.0;
    #pragma unroll
    for (int k = 0; k < TOPK; ++k)
      if (slab[k] == tid) a += wv32[k];
    float r2 = (float)(a + 1e-5);
    out[(size_t)row * NCLS + tid] = fminf(r2, 1.0f);
  }
}

// ---------------------------------------------------------------------------
extern "C" void kernel_launch(void* const* d_in, const int* in_sizes, int n_in,
                              void* d_out, int out_size, void* d_ws, size_t ws_size,
                              hipStream_t stream) {
  const float* x = (const float*)d_in[0];
  const float* mem = (const float*)d_in[1];
  const int* labels = (const int*)d_in[2];
  float* out = (float*)d_out;
  char* ws = (char*)d_ws;

  // workspace layout (needs ~7 MB)
  float* xn = (float*)ws;                            //   2,097,152 B
  u8* xnb8 = (u8*)(ws + 2097152);                    //     524,288 B
  int* cnt = (int*)(ws + 2621440);                   //       4,096 B
  int* ccol = (int*)(ws + 2625536);                  //   4,194,304 B

  normalize_x<<<dim3(B_ROWS), dim3(256), 0, stream>>>(x, xn, xnb8, cnt);
  gemm_filter<<<dim3(512), dim3(512), 0, stream>>>(xnb8, mem, cnt, ccol);
  rescore_vote<<<dim3(B_ROWS), dim3(256), 0, stream>>>(xn, mem, labels, cnt,
                                                       ccol, out);
}

// Round 21
// 180.979 us; speedup vs baseline: 1.3894x; 1.3894x over previous
//
#include <hip/hip_runtime.h>

typedef unsigned short u16;
typedef unsigned char u8;
typedef __attribute__((ext_vector_type(4))) float f32x4;

#define B_ROWS 1024
#define DIM 512
#define QN 131072
#define TOPK 32
#define NCLS 10
#define TAUS 35.84f   /* 0.14 * 256 (both operands scaled x16) */
#define CAP 1024
#define FP8SCALE 16.0f

#define S_VMCNT(N) asm volatile("s_waitcnt vmcnt(" #N ")" ::: "memory")
#define S_BAR() asm volatile("s_barrier" ::: "memory")
#define S_LGKM0() asm volatile("s_waitcnt lgkmcnt(0)" ::: "memory")

__device__ __forceinline__ void gload_lds16(const void* gsrc, void* ldst) {
  __builtin_amdgcn_global_load_lds(
      (const __attribute__((address_space(1))) void*)gsrc,
      (__attribute__((address_space(3))) void*)ldst, 16, 0, 0);
}

// pack 4 floats -> 4 fp8 e4m3 bytes (HW cvt). Same packer for A and B, so
// any byte-order convention cancels in the dot product.
__device__ __forceinline__ int pk4(float a, float b, float c, float d) {
  int w = __builtin_amdgcn_cvt_pk_fp8_f32(a, b, 0, false);
  w = __builtin_amdgcn_cvt_pk_fp8_f32(c, d, w, true);
  return w;
}

// ---------------------------------------------------------------- normalize x
// fp32 normalized row -> xn; fp8(x16) k-permuted row -> xnb8; zeroes cnt.
// Permuted layout per 64-k chunk c: 16B slot t = {k c*64+t*8..+8} ++
// {k c*64+32+t*8..+8}.
__global__ __launch_bounds__(256) void normalize_x(const float* __restrict__ x,
                                                   float* __restrict__ xn,
                                                   u8* __restrict__ xnb8,
                                                   int* __restrict__ cnt) {
  int row = blockIdx.x;
  int tid = threadIdx.x;
  __shared__ float xs[DIM];
  __shared__ float wsum[4];
  if (tid == 0) cnt[row] = 0;
  float2 v = ((const float2*)(x + (size_t)row * DIM))[tid];
  float ss = v.x * v.x + v.y * v.y;
  #pragma unroll
  for (int o = 32; o; o >>= 1) ss += __shfl_xor(ss, o);
  if ((tid & 63) == 0) wsum[tid >> 6] = ss;
  __syncthreads();
  float tot = wsum[0] + wsum[1] + wsum[2] + wsum[3];
  float scale = 1.0f / fmaxf(sqrtf(tot), 1e-12f);
  float2 o2; o2.x = v.x * scale; o2.y = v.y * scale;
  ((float2*)(xn + (size_t)row * DIM))[tid] = o2;
  xs[2 * tid] = o2.x; xs[2 * tid + 1] = o2.y;
  __syncthreads();
  if (tid < 32) {  // 32 slots of 16B per row (k-permuted fp8)
    int c = tid >> 2, t4 = tid & 3;
    int k0 = c * 64 + t4 * 8;
    int4 w;
    w.x = pk4(xs[k0+0]*FP8SCALE, xs[k0+1]*FP8SCALE, xs[k0+2]*FP8SCALE, xs[k0+3]*FP8SCALE);
    w.y = pk4(xs[k0+4]*FP8SCALE, xs[k0+5]*FP8SCALE, xs[k0+6]*FP8SCALE, xs[k0+7]*FP8SCALE);
    w.z = pk4(xs[k0+32]*FP8SCALE, xs[k0+33]*FP8SCALE, xs[k0+34]*FP8SCALE, xs[k0+35]*FP8SCALE);
    w.w = pk4(xs[k0+36]*FP8SCALE, xs[k0+37]*FP8SCALE, xs[k0+38]*FP8SCALE, xs[k0+39]*FP8SCALE);
    ((int4*)(xnb8 + (size_t)row * DIM))[tid] = w;
  }
}

// ---------------------- fp8 MFMA GEMM + in-kernel B conversion + filter
// R19 VERBATIM (proven 177.4us best, absmax 0). BN=128, 8 waves (512 thr),
// BM=256, K-step 64, 8 steps; A via 2-slot gload_lds queue dist-1, B
// reg-staged fp32->fp8 2-slot ds_write queue dist-2; one s_barrier/step;
// counted vmcnt by queue enumeration:
//   prologue: issuePB(0)x4, stageA(0)x2; vmcnt(2) retires PB(0) only;
//             writeB(0); issuePB(1); lgkm0
//   pt1: queue [A(h)x2, PB(h+1)x4] -> vmcnt(4) retires A(h)   (h=7: 0)
//   pt2: stageA(h+1)x2                                        [h<7]
//   pt3: ds_read A x4 + B x4 (b128); 32 MFMA (setprio wrap)
//   pt4: queue [PB(h+1)x4, A(h+1)x2] -> vmcnt(2) retires PB(h+1);
//        writeB(h+1) [h<7]; issuePB(h+2) [h<6]; lgkm0
// Race proofs: lgkm0-before-barrier (LDS WAR), in-order vmcnt retirement
// (landing). Swizzle involution: phys = g ^ ((L>>1)&3) read-side, sg
// source-side (0 conflicts measured R6-R19).
// CLOSED LEVERS (all A/B'd): 32x32 MFMA shapes (R13/R16: conflicts+spill),
// mid-step writeB / no-setprio / 8-lane rescore (R17), persistent blocks
// (R20: L2 locality loss, +65us), mega-fusion (R8), barrier-free (R12),
// direct-global A (R12), occupancy>4 (impossible: 64 AGPR acc).
__global__ __launch_bounds__(512, 4) void gemm_filter(const u8* __restrict__ xnb8,
                                                      const float* __restrict__ mem,
                                                      int* __restrict__ cnt,
                                                      int* __restrict__ ccol) {
  __shared__ __attribute__((aligned(16))) u8 As[2][16384];
  __shared__ __attribute__((aligned(16))) u8 Bs[2][8192];
  int bid = blockIdx.x;
  // XCD-aware: the 4 row-sharers of a B-panel sit on one XCD
  int xcd = bid & 7;
  int i = bid >> 3;
  int colt = xcd * 128 + (i >> 2);
  int rowt = i & 3;
  int row0 = rowt * 256;
  int col0 = colt * 128;
  int tid = threadIdx.x;
  int lane = tid & 63;
  int wv = tid >> 6;          // 0..7
  int wr = wv >> 1, wc = wv & 1;

  // staging geometry: logical k-slot sg = (tid&3) ^ ((r>>1)&3); A chunk jj
  // covers row r = jj*128 + (tid>>2) ((r>>1)&3 == (tid>>3)&3 for both jj);
  // B covers row r = tid>>2 (one 16B unit per thread).
  int sg = (tid & 3) ^ ((tid >> 3) & 3);
  const u8* gAb = xnb8 + (size_t)(row0 + (tid >> 2)) * DIM + sg * 16;
  const float* gB = mem + (size_t)(col0 + (tid >> 2)) * DIM + sg * 8;

  // read side: lane L = row-within-16; phys slot = g ^ ((L>>1)&3)
  int L = lane & 15;
  int g = lane >> 4;
  int phys = g ^ ((L >> 1) & 3);
  int offA = (wr * 64 + L) * 64 + phys * 16;   // bytes, + m*1024
  int offB = (wc * 64 + L) * 64 + phys * 16;   // bytes, + n*1024

  f32x4 acc[4][4];
  #pragma unroll
  for (int m = 0; m < 4; ++m)
    #pragma unroll
    for (int n = 0; n < 4; ++n) acc[m][n] = (f32x4){0.f, 0.f, 0.f, 0.f};

  float4 pb[4];  // B prefetch regs: 16 floats (16 VGPR)

  auto stageA = [&](int h) {
    int slot = h & 1;
    #pragma unroll
    for (int jj = 0; jj < 2; ++jj)
      gload_lds16(gAb + (size_t)jj * 65536 + h * 64,
                  &As[slot][jj * 8192 + tid * 16]);
  };
  auto issuePB = [&](int h) {
    const float4* s = (const float4*)(gB + h * 64);
    pb[0] = s[0]; pb[1] = s[1];   // k sg*8..+8
    pb[2] = s[8]; pb[3] = s[9];   // k 32+sg*8..+8
  };
  auto writeB = [&](int h) {
    int slot = h & 1;
    int4 w;
    w.x = pk4(pb[0].x*FP8SCALE, pb[0].y*FP8SCALE, pb[0].z*FP8SCALE, pb[0].w*FP8SCALE);
    w.y = pk4(pb[1].x*FP8SCALE, pb[1].y*FP8SCALE, pb[1].z*FP8SCALE, pb[1].w*FP8SCALE);
    w.z = pk4(pb[2].x*FP8SCALE, pb[2].y*FP8SCALE, pb[2].z*FP8SCALE, pb[2].w*FP8SCALE);
    w.w = pk4(pb[3].x*FP8SCALE, pb[3].y*FP8SCALE, pb[3].z*FP8SCALE, pb[3].w*FP8SCALE);
    *(int4*)&Bs[slot][tid * 16] = w;
  };

  union I4L { int4 v; long l[2]; };

  // prologue: PB(0) first, then A(0); vmcnt(2) retires PB(0) only (A(0)
  // keeps flying -- retired by loop-h0's vmcnt(4)+barrier).
  issuePB(0); stageA(0);
  S_VMCNT(2);
  writeB(0);
  issuePB(1);
  S_LGKM0();

  #pragma unroll
  for (int h = 0; h < 8; ++h) {
    if (h < 7) { S_VMCNT(4); }   // retires A(h)x2; keeps PB(h+1)x4 flying
    else { S_VMCNT(0); }         // h=7: drains A(7)
    S_BAR();
    if (h < 7) stageA(h + 1);
    const u8* Ab = &As[h & 1][0];
    const u8* Bb = &Bs[h & 1][0];
    I4L av[4], bv[4];
    #pragma unroll
    for (int m = 0; m < 4; ++m) av[m].v = *(const int4*)(Ab + offA + m * 1024);
    #pragma unroll
    for (int n = 0; n < 4; ++n) bv[n].v = *(const int4*)(Bb + offB + n * 1024);
    __builtin_amdgcn_s_setprio(1);
    #pragma unroll
    for (int m = 0; m < 4; ++m)
      #pragma unroll
      for (int n = 0; n < 4; ++n)
        acc[m][n] = __builtin_amdgcn_mfma_f32_16x16x32_fp8_fp8(
            av[m].l[0], bv[n].l[0], acc[m][n], 0, 0, 0);
    #pragma unroll
    for (int m = 0; m < 4; ++m)
      #pragma unroll
      for (int n = 0; n < 4; ++n)
        acc[m][n] = __builtin_amdgcn_mfma_f32_16x16x32_fp8_fp8(
            av[m].l[1], bv[n].l[1], acc[m][n], 0, 0, 0);
    __builtin_amdgcn_s_setprio(0);
    if (h < 7) {
      S_VMCNT(2);                // retires PB(h+1)x4; keeps A(h+1)x2 flying
      writeB(h + 1);
      if (h < 6) issuePB(h + 2);
      S_LGKM0();                 // ds ops retired before next barrier
    }
  }

  // epilogue: D row=(lane>>4)*4+q, col=lane&15 (dtype-independent layout)
  int rbase = row0 + wr * 64 + (lane >> 4) * 4;
  int cbase = col0 + wc * 64 + (lane & 15);
  #pragma unroll
  for (int m = 0; m < 4; ++m)
    #pragma unroll
    for (int n = 0; n < 4; ++n)
      #pragma unroll
      for (int q = 0; q < 4; ++q) {
        float v = acc[m][n][q];
        if (v > TAUS) {
          int grow = rbase + m * 16 + q;
          int gcol = cbase + n * 16;
          int idx = atomicAdd(&cnt[grow], 1);
          if (idx < CAP) ccol[(size_t)grow * CAP + idx] = gcol;
        }
      }
}

// ------------------------------- exact rescore + top-32 + softmax vote
// (R15 VERBATIM -- validated absmax 0.0; 16-lane groups: R17 showed 8-lane
// regresses ~+19us)
__global__ __launch_bounds__(256) void rescore_vote(const float* __restrict__ xn,
                                                    const float* __restrict__ mem,
                                                    const int* __restrict__ labels,
                                                    const int* __restrict__ cnt,
                                                    const int* __restrict__ ccol,
                                                    float* __restrict__ out) {
  int row = blockIdx.x;
  int tid = threadIdx.x;
  int gid = tid >> 4;          // 16 groups
  int gl = tid & 15;           // lane within group
  __shared__ __attribute__((aligned(16))) float xs[DIM];
  __shared__ double sv[CAP];
  __shared__ int sc[CAP];
  __shared__ double selv[TOPK];
  __shared__ int selc[TOPK];
  __shared__ double wv32[TOPK];
  __shared__ int slab[TOPK];

  ((float2*)xs)[tid] = ((const float2*)(xn + (size_t)row * DIM))[tid];
  if (tid < TOPK) { selv[tid] = -1e300; selc[tid] = 0; }
  int count = cnt[row];
  if (count > CAP) count = CAP;
  __syncthreads();

  // dot phase: one 16-lane group per candidate, fp64 accumulate
  for (int c = gid; c < count; c += 16) {
    int col = ccol[(size_t)row * CAP + c];
    const float4* mp = (const float4*)(mem + (size_t)col * DIM);
    const float4* xp = (const float4*)xs;
    double p = 0.0;
    #pragma unroll
    for (int u = 0; u < 8; ++u) {
      float4 mv = mp[u * 16 + gl];
      float4 xv = xp[u * 16 + gl];
      p += (double)mv.x * xv.x + (double)mv.y * xv.y +
           (double)mv.z * xv.z + (double)mv.w * xv.w;
    }
    #pragma unroll
    for (int o = 8; o; o >>= 1) p += __shfl_xor(p, o);
    if (gl == 0) { sv[c] = p; sc[c] = col; }
  }
  __syncthreads();

  // rank-based top-32: rank = #{j: v_j > v or (v_j==v && col_j < col)}
  for (int c = tid; c < count; c += 256) {
    double v = sv[c]; int cc = sc[c];
    int r = 0;
    for (int j = 0; j < count; ++j) {
      double vj = sv[j]; int cj = sc[j];
      r += (vj > v) || (vj == v && cj < cc);
    }
    if (r < TOPK) { selv[r] = v; selc[r] = cc; }
  }
  __syncthreads();

  // softmax(sim/0.1) + one-hot vote
  if (tid < TOPK) {
    slab[tid] = labels[selc[tid]];
    double e = exp((selv[tid] - selv[0]) * 10.0);
    double s = e;
    #pragma unroll
    for (int o = 16; o; o >>= 1) s += __shfl_xor(s, o, 32);
    wv32[tid] = e / s;
  }
  __syncthreads();
  if (tid < NCLS) {
    double a = 0.0;
    #pragma unroll
    for (int k = 0; k < TOPK; ++k)
      if (slab[k] == tid) a += wv32[k];
    float r2 = (float)(a + 1e-5);
    out[(size_t)row * NCLS + tid] = fminf(r2, 1.0f);
  }
}

// ---------------------------------------------------------------------------
extern "C" void kernel_launch(void* const* d_in, const int* in_sizes, int n_in,
                              void* d_out, int out_size, void* d_ws, size_t ws_size,
                              hipStream_t stream) {
  const float* x = (const float*)d_in[0];
  const float* mem = (const float*)d_in[1];
  const int* labels = (const int*)d_in[2];
  float* out = (float*)d_out;
  char* ws = (char*)d_ws;

  // workspace layout (needs ~7 MB)
  float* xn = (float*)ws;                            //   2,097,152 B
  u8* xnb8 = (u8*)(ws + 2097152);                    //     524,288 B
  int* cnt = (int*)(ws + 2621440);                   //       4,096 B
  int* ccol = (int*)(ws + 2625536);                  //   4,194,304 B

  normalize_x<<<dim3(B_ROWS), dim3(256), 0, stream>>>(x, xn, xnb8, cnt);
  gemm_filter<<<dim3((B_ROWS / 256) * (QN / 128)), dim3(512), 0, stream>>>(
      xnb8, mem, cnt, ccol);
  rescore_vote<<<dim3(B_ROWS), dim3(256), 0, stream>>>(xn, mem, labels, cnt,
                                                       ccol, out);
}